// Round 8
// baseline (1102.879 us; speedup 1.0000x reference)
//
#include <hip/hip_runtime.h>
#include <hip/hip_fp16.h>
#include <math.h>

// CapsuleLayer dynamic routing, fused recompute formulation.
// x[B=128, J=2048, I=8], W[J, K=32, I, D=16] -> v[B, K, D]
// b_t = (sum_{tau<t} v_tau) . u_hat, so keep only vsum[b,k,d] and recompute
// u_hat each sweep.
//
// R6 -> R7: R6's prep'd bf16-W-in-d_ws caused +55MB fetch / +79MB write per
// sweep (poison/writeback churn on d_ws) -> 122us. Revert to sourcing W from
// the pristine input buffer (R5's clean 28/28MB profile), but keep the LDS
// byte-halving by converting fp32->f16 IN-KERNEL via reg-staging:
// load 64B/thread fp32 (coalesced) -> cvt f16 -> ds_write_b128 pre-swizzled.
// Loads for j+2 issue right after the ds_write of j+1 (latency hides under a
// full compute phase). One barrier per j. f16 W (|W|<~0.3) has rel err 2^-11,
// better than R6's bf16. LDS bank pattern is at the 1KB/instr throughput
// floor on both read and write sides (8 lanes per bank-quad, distinct addrs).
// R7 -> R8: R7 never ran (container failed twice). Resubmitting unchanged.

constexpr int Bn = 128;
constexpr int Jn = 2048;
constexpr int In = 8;
constexpr int Kn = 32;
constexpr int Dn = 16;
constexpr int KD = Kn * Dn;          // 512
constexpr int CELLS = Bn * KD;       // 65536

constexpr int JT    = 32;            // j per workgroup
constexpr int NJB   = Jn / JT;       // 64 j-blocks
constexpr int WAVES = 4;
constexpr int BLOCK = WAVES * 64;    // 256 threads
constexpr int BW    = 2;             // batches per wave
constexpr int BGW   = WAVES * BW;    // 8 batches per workgroup
constexpr int NBB   = Bn / BGW;      // 16 b-blocks
constexpr int GRID_SWEEP = NBB * NJB; // 1024 workgroups = 4/CU
constexpr int SLICE = Kn * In * Dn * 2;  // 8192 B per j (f16)

// swizzle involution on a slice-local byte offset (bits 4-6 ^= bits 8-10)
__device__ __forceinline__ int swz(int L) { return L ^ (((L >> 8) & 7) << 4); }

__device__ __forceinline__ unsigned pk2(float a, float b) {
    const __half2 h = __floats2half2_rn(a, b);
    return *reinterpret_cast<const unsigned*>(&h);
}

// issue this thread's 64B (16 fp32) of slice j into registers
__device__ __forceinline__ void issue_loads(const float* __restrict__ W,
                                            int jidx, int tid, float4 (&st)[4])
{
    const float* p = W + (size_t)jidx * 4096 + tid * 8;
    st[0] = *reinterpret_cast<const float4*>(p);
    st[1] = *reinterpret_cast<const float4*>(p + 4);
    st[2] = *reinterpret_cast<const float4*>(p + 2048);
    st[3] = *reinterpret_cast<const float4*>(p + 2052);
}

// convert to f16 and write both 16B slots, pre-swizzled
__device__ __forceinline__ void write_stage(char* ldsbase, int tid,
                                            const float4 (&st)[4])
{
    uint4 u0, u1;
    u0.x = pk2(st[0].x, st[0].y); u0.y = pk2(st[0].z, st[0].w);
    u0.z = pk2(st[1].x, st[1].y); u0.w = pk2(st[1].z, st[1].w);
    u1.x = pk2(st[2].x, st[2].y); u1.y = pk2(st[2].z, st[2].w);
    u1.z = pk2(st[3].x, st[3].y); u1.w = pk2(st[3].z, st[3].w);
    const int L0 = tid * 16;            // logical slot tid
    const int L1 = tid * 16 + 4096;     // logical slot tid+256
    *reinterpret_cast<uint4*>(ldsbase + swz(L0)) = u0;
    *reinterpret_cast<uint4*>(ldsbase + swz(L1)) = u1;
}

// PHASE: 0 = uniform c (softmax of zeros), 1/2 = softmax(vsum . u_hat)
template <int PHASE, bool ATOMIC>
__global__ __launch_bounds__(BLOCK, 4)
void sweep_kernel(const float* __restrict__ x, const float* __restrict__ W,
                  const float* __restrict__ vsum, float* __restrict__ sout)
{
    __shared__ __align__(16) char wlds[2 * SLICE];   // 16 KB double buffer

    const int jb    = blockIdx.x % NJB;
    const int b0    = (blockIdx.x / NJB) * BGW;
    const int tid   = threadIdx.x;
    const int wave  = tid >> 6;
    const int lane  = tid & 63;
    const int kk    = lane >> 1;             // output capsule
    const int dh    = lane & 1;              // d-half (8 values)
    const int bbase = b0 + wave * BW;
    const int kswz  = (kk & 7) << 4;         // read-side swizzle key
    const int Lb    = kk * 256 + dh * 16;    // f16 slice base byte

    // vsum[b, kk, dh*8..+8] is j-invariant: hoist to registers.
    float vs[BW][8];
    if (PHASE != 0) {
#pragma unroll
        for (int bb = 0; bb < BW; ++bb) {
            const float* vp = vsum + ((size_t)(bbase + bb) * Kn + kk) * Dn + dh * 8;
            const float4 a  = *reinterpret_cast<const float4*>(vp);
            const float4 b4 = *reinterpret_cast<const float4*>(vp + 4);
            vs[bb][0] = a.x;  vs[bb][1] = a.y;  vs[bb][2] = a.z;  vs[bb][3] = a.w;
            vs[bb][4] = b4.x; vs[bb][5] = b4.y; vs[bb][6] = b4.z; vs[bb][7] = b4.w;
        }
    }

    float sacc[BW][8];
#pragma unroll
    for (int bb = 0; bb < BW; ++bb)
#pragma unroll
        for (int r = 0; r < 8; ++r) sacc[bb][r] = 0.f;

    const int j0 = jb * JT;
    float4 st[4];
    issue_loads(W, j0, tid, st);
    write_stage(wlds, tid, st);          // waits on st via reg dependency
    issue_loads(W, j0 + 1, tid, st);     // j1 in flight across the barrier
    __syncthreads();                     // buf0 ready

#pragma unroll 2
    for (int jj = 0; jj < JT; ++jj) {
        const int j   = j0 + jj;
        const int buf = jj & 1;

        // x[b, j, 0..7]: wave-uniform broadcast loads (independent of LDS)
        float xv[BW][8];
#pragma unroll
        for (int bb = 0; bb < BW; ++bb) {
            const float* xp = x + ((size_t)(bbase + bb) * Jn + j) * In;
            const float4 xa = *reinterpret_cast<const float4*>(xp);
            const float4 xb = *reinterpret_cast<const float4*>(xp + 4);
            xv[bb][0] = xa.x; xv[bb][1] = xa.y; xv[bb][2] = xa.z; xv[bb][3] = xa.w;
            xv[bb][4] = xb.x; xv[bb][5] = xb.y; xv[bb][6] = xb.z; xv[bb][7] = xb.w;
        }

        // u_hat[b, kk, j, dh*8+r] = sum_i x[b,j,i] * W[j,kk,i,dh*8+r]
        float uh[BW][8];
#pragma unroll
        for (int bb = 0; bb < BW; ++bb)
#pragma unroll
            for (int r = 0; r < 8; ++r) uh[bb][r] = 0.f;

        const char* wb = wlds + buf * SLICE;
#pragma unroll
        for (int i = 0; i < In; ++i) {
            const uint4 wv = *reinterpret_cast<const uint4*>(wb + ((Lb + i * 32) ^ kswz));
            float w8[8];
            {
                const __half2 h0 = *reinterpret_cast<const __half2*>(&wv.x);
                const __half2 h1 = *reinterpret_cast<const __half2*>(&wv.y);
                const __half2 h2 = *reinterpret_cast<const __half2*>(&wv.z);
                const __half2 h3 = *reinterpret_cast<const __half2*>(&wv.w);
                w8[0] = __low2float(h0); w8[1] = __high2float(h0);
                w8[2] = __low2float(h1); w8[3] = __high2float(h1);
                w8[4] = __low2float(h2); w8[5] = __high2float(h2);
                w8[6] = __low2float(h3); w8[7] = __high2float(h3);
            }
#pragma unroll
            for (int bb = 0; bb < BW; ++bb)
#pragma unroll
                for (int r = 0; r < 8; ++r)
                    uh[bb][r] = fmaf(xv[bb][i], w8[r], uh[bb][r]);
        }

        if (PHASE == 0) {
#pragma unroll
            for (int bb = 0; bb < BW; ++bb)
#pragma unroll
                for (int r = 0; r < 8; ++r) sacc[bb][r] += uh[bb][r];
        } else {
#pragma unroll
            for (int bb = 0; bb < BW; ++bb) {
                float p = vs[bb][0] * uh[bb][0];
#pragma unroll
                for (int r = 1; r < 8; ++r) p = fmaf(vs[bb][r], uh[bb][r], p);
                p += __shfl_xor(p, 1);   // combine d-halves -> full dot

                // no max-subtraction: |p| <= ~12 << 88, exp can't overflow.
                // masks 2..32 mix only same-parity lanes -> each k once.
                const float e = __expf(p);
                float ss = e;
#pragma unroll
                for (int mk = 2; mk <= 32; mk <<= 1)
                    ss += __shfl_xor(ss, mk);
#if __has_builtin(__builtin_amdgcn_rcpf)
                const float c = e * __builtin_amdgcn_rcpf(ss);
#else
                const float c = e / ss;
#endif
#pragma unroll
                for (int r = 0; r < 8; ++r)
                    sacc[bb][r] = fmaf(c, uh[bb][r], sacc[bb][r]);
            }
        }

        // finish the j+1 stage (regs arrived during compute), then issue j+2
        if (jj + 1 < JT) {
            write_stage(wlds + (buf ^ 1) * SLICE, tid, st);
            if (jj + 2 < JT) issue_loads(W, j0 + jj + 2, tid, st);
        }
        __syncthreads();   // buf reads done + next buf written
    }

    // epilogue: dump per-wave s partials
#pragma unroll
    for (int bb = 0; bb < BW; ++bb) {
        const int b = bbase + bb;
        const size_t cell = ((size_t)b * Kn + kk) * Dn + dh * 8;
        if (ATOMIC) {
#pragma unroll
            for (int r = 0; r < 8; ++r)
                atomicAdd(sout + cell + r, sacc[bb][r]);
        } else {
            const float4 f0 = make_float4(sacc[bb][0], sacc[bb][1], sacc[bb][2], sacc[bb][3]);
            const float4 f1 = make_float4(sacc[bb][4], sacc[bb][5], sacc[bb][6], sacc[bb][7]);
            float* dst = sout + (size_t)jb * CELLS + cell;
            *reinterpret_cast<float4*>(dst)     = f0;
            *reinterpret_cast<float4*>(dst + 4) = f1;
        }
    }
}

// Reduce partials, squash, update vsum; final phase writes v to d_out.
template <int PHASE, bool ATOMIC>
__global__ __launch_bounds__(256)
void squash_kernel(float* __restrict__ sbuf, float* __restrict__ vsum,
                   float* __restrict__ outv)
{
    const int t = blockIdx.x * blockDim.x + threadIdx.x;   // 0..16383
    const size_t c4 = (size_t)t * 4;

    float4 s;
    if (ATOMIC) {
        s = *reinterpret_cast<const float4*>(sbuf + c4);
        *reinterpret_cast<float4*>(sbuf + c4) = make_float4(0.f, 0.f, 0.f, 0.f);
    } else {
        s = make_float4(0.f, 0.f, 0.f, 0.f);
#pragma unroll 4
        for (int p = 0; p < NJB; ++p) {
            const float4 v = *reinterpret_cast<const float4*>(sbuf + (size_t)p * CELLS + c4);
            s.x += v.x; s.y += v.y; s.z += v.z; s.w += v.w;
        }
    }

    if (PHASE == 0) {  // uniform c = 1/K folded out of the sweep
        const float sc = 1.f / 32.f;
        s.x *= sc; s.y *= sc; s.z *= sc; s.w *= sc;
    }

    float s2 = s.x * s.x + s.y * s.y + s.z * s.z + s.w * s.w;
    s2 += __shfl_xor(s2, 1);
    s2 += __shfl_xor(s2, 2);
    const float scale = s2 / ((1.f + s2) * sqrtf(s2 + 1e-7f));
    const float4 v4 = make_float4(s.x * scale, s.y * scale, s.z * scale, s.w * scale);

    if (PHASE == 2) {
        *reinterpret_cast<float4*>(outv + c4) = v4;
    } else if (PHASE == 0) {
        *reinterpret_cast<float4*>(vsum + c4) = v4;
    } else {
        float4 o = *reinterpret_cast<const float4*>(vsum + c4);
        o.x += v4.x; o.y += v4.y; o.z += v4.z; o.w += v4.w;
        *reinterpret_cast<float4*>(vsum + c4) = o;
    }
}

extern "C" void kernel_launch(void* const* d_in, const int* in_sizes, int n_in,
                              void* d_out, int out_size, void* d_ws, size_t ws_size,
                              hipStream_t stream)
{
    const float* x = (const float*)d_in[0];
    const float* W = (const float*)d_in[1];
    float* out = (float*)d_out;

    const size_t partial_bytes = (size_t)NJB * CELLS * sizeof(float);  // 16 MB
    const size_t vsum_bytes    = (size_t)CELLS * sizeof(float);        // 256 KB

    const dim3 gs(GRID_SWEEP), bs(BLOCK);
    const dim3 gq(CELLS / 4 / 256), bq(256);

    if (ws_size >= partial_bytes + vsum_bytes) {
        float* partial = (float*)d_ws;
        float* vsum    = (float*)((char*)d_ws + partial_bytes);
        sweep_kernel<0, false><<<gs, bs, 0, stream>>>(x, W, vsum, partial);
        squash_kernel<0, false><<<gq, bq, 0, stream>>>(partial, vsum, out);
        sweep_kernel<1, false><<<gs, bs, 0, stream>>>(x, W, vsum, partial);
        squash_kernel<1, false><<<gq, bq, 0, stream>>>(partial, vsum, out);
        sweep_kernel<2, false><<<gs, bs, 0, stream>>>(x, W, vsum, partial);
        squash_kernel<2, false><<<gq, bq, 0, stream>>>(partial, vsum, out);
    } else {
        // tiny-workspace fallback: single accumulator + atomics
        float* sbuf = (float*)d_ws;
        float* vsum = (float*)((char*)d_ws + vsum_bytes);
        hipMemsetAsync(sbuf, 0, vsum_bytes, stream);
        sweep_kernel<0, true><<<gs, bs, 0, stream>>>(x, W, vsum, sbuf);
        squash_kernel<0, true><<<gq, bq, 0, stream>>>(sbuf, vsum, out);
        sweep_kernel<1, true><<<gs, bs, 0, stream>>>(x, W, vsum, sbuf);
        squash_kernel<1, true><<<gq, bq, 0, stream>>>(sbuf, vsum, out);
        sweep_kernel<2, true><<<gs, bs, 0, stream>>>(x, W, vsum, sbuf);
        squash_kernel<2, true><<<gq, bq, 0, stream>>>(sbuf, vsum, out);
    }
}

// Round 11
// 977.662 us; speedup vs baseline: 1.1281x; 1.1281x over previous
//
#include <hip/hip_runtime.h>
#include <hip/hip_fp16.h>
#include <math.h>

// CapsuleLayer dynamic routing, fused recompute formulation.
// x[B=128, J=2048, I=8], W[J, K=32, I, D=16] -> v[B, K, D]
// b_t = (sum_{tau<t} v_tau) . u_hat, so keep only vsum[b,k,d] and recompute
// u_hat each sweep.
//
// R8 -> R9: R8's counters showed the f16 reg-staged pipeline SPILLING:
// VGPR_Count=64 (compiler over-achieved the launch_bounds MINIMUM to 8
// waves/SIMD) while the live set is ~110 -> 830MB/sweep scratch writes,
// sweeps 360us, one 41ms scratch-churn outlier. Fix: pin occupancy with
// amdgpu_waves_per_eu(4,4) -> VGPR budget 128, live set fits, no spills.
// Everything else (f16 LDS halving, swizzle, stage pipeline) unchanged.
// R9/R10 never ran (infra). Resubmitting unchanged.

constexpr int Bn = 128;
constexpr int Jn = 2048;
constexpr int In = 8;
constexpr int Kn = 32;
constexpr int Dn = 16;
constexpr int KD = Kn * Dn;          // 512
constexpr int CELLS = Bn * KD;       // 65536

constexpr int JT    = 32;            // j per workgroup
constexpr int NJB   = Jn / JT;       // 64 j-blocks
constexpr int WAVES = 4;
constexpr int BLOCK = WAVES * 64;    // 256 threads
constexpr int BW    = 2;             // batches per wave
constexpr int BGW   = WAVES * BW;    // 8 batches per workgroup
constexpr int NBB   = Bn / BGW;      // 16 b-blocks
constexpr int GRID_SWEEP = NBB * NJB; // 1024 workgroups = 4/CU
constexpr int SLICE = Kn * In * Dn * 2;  // 8192 B per j (f16)

// swizzle involution on a slice-local byte offset (bits 4-6 ^= bits 8-10)
__device__ __forceinline__ int swz(int L) { return L ^ (((L >> 8) & 7) << 4); }

__device__ __forceinline__ unsigned pk2(float a, float b) {
    const __half2 h = __floats2half2_rn(a, b);
    return *reinterpret_cast<const unsigned*>(&h);
}

// issue this thread's 64B (16 fp32) of slice j into registers
__device__ __forceinline__ void issue_loads(const float* __restrict__ W,
                                            int jidx, int tid, float4 (&st)[4])
{
    const float* p = W + (size_t)jidx * 4096 + tid * 8;
    st[0] = *reinterpret_cast<const float4*>(p);
    st[1] = *reinterpret_cast<const float4*>(p + 4);
    st[2] = *reinterpret_cast<const float4*>(p + 2048);
    st[3] = *reinterpret_cast<const float4*>(p + 2052);
}

// convert to f16 and write both 16B slots, pre-swizzled
__device__ __forceinline__ void write_stage(char* ldsbase, int tid,
                                            const float4 (&st)[4])
{
    uint4 u0, u1;
    u0.x = pk2(st[0].x, st[0].y); u0.y = pk2(st[0].z, st[0].w);
    u0.z = pk2(st[1].x, st[1].y); u0.w = pk2(st[1].z, st[1].w);
    u1.x = pk2(st[2].x, st[2].y); u1.y = pk2(st[2].z, st[2].w);
    u1.z = pk2(st[3].x, st[3].y); u1.w = pk2(st[3].z, st[3].w);
    const int L0 = tid * 16;            // logical slot tid
    const int L1 = tid * 16 + 4096;     // logical slot tid+256
    *reinterpret_cast<uint4*>(ldsbase + swz(L0)) = u0;
    *reinterpret_cast<uint4*>(ldsbase + swz(L1)) = u1;
}

// PHASE: 0 = uniform c (softmax of zeros), 1/2 = softmax(vsum . u_hat)
template <int PHASE, bool ATOMIC>
__global__ __launch_bounds__(BLOCK)
__attribute__((amdgpu_waves_per_eu(4, 4)))   // pin 4 waves/SIMD -> 128 VGPR, no spills
void sweep_kernel(const float* __restrict__ x, const float* __restrict__ W,
                  const float* __restrict__ vsum, float* __restrict__ sout)
{
    __shared__ __align__(16) char wlds[2 * SLICE];   // 16 KB double buffer

    const int jb    = blockIdx.x % NJB;
    const int b0    = (blockIdx.x / NJB) * BGW;
    const int tid   = threadIdx.x;
    const int wave  = tid >> 6;
    const int lane  = tid & 63;
    const int kk    = lane >> 1;             // output capsule
    const int dh    = lane & 1;              // d-half (8 values)
    const int bbase = b0 + wave * BW;
    const int kswz  = (kk & 7) << 4;         // read-side swizzle key
    const int Lb    = kk * 256 + dh * 16;    // f16 slice base byte

    // vsum[b, kk, dh*8..+8] is j-invariant: hoist to registers.
    float vs[BW][8];
    if (PHASE != 0) {
#pragma unroll
        for (int bb = 0; bb < BW; ++bb) {
            const float* vp = vsum + ((size_t)(bbase + bb) * Kn + kk) * Dn + dh * 8;
            const float4 a  = *reinterpret_cast<const float4*>(vp);
            const float4 b4 = *reinterpret_cast<const float4*>(vp + 4);
            vs[bb][0] = a.x;  vs[bb][1] = a.y;  vs[bb][2] = a.z;  vs[bb][3] = a.w;
            vs[bb][4] = b4.x; vs[bb][5] = b4.y; vs[bb][6] = b4.z; vs[bb][7] = b4.w;
        }
    }

    float sacc[BW][8];
#pragma unroll
    for (int bb = 0; bb < BW; ++bb)
#pragma unroll
        for (int r = 0; r < 8; ++r) sacc[bb][r] = 0.f;

    const int j0 = jb * JT;
    float4 st[4];
    issue_loads(W, j0, tid, st);
    write_stage(wlds, tid, st);          // waits on st via reg dependency
    issue_loads(W, j0 + 1, tid, st);     // j1 in flight across the barrier
    __syncthreads();                     // buf0 ready

#pragma unroll 2
    for (int jj = 0; jj < JT; ++jj) {
        const int j   = j0 + jj;
        const int buf = jj & 1;

        // x[b, j, 0..7]: wave-uniform broadcast loads (independent of LDS)
        float xv[BW][8];
#pragma unroll
        for (int bb = 0; bb < BW; ++bb) {
            const float* xp = x + ((size_t)(bbase + bb) * Jn + j) * In;
            const float4 xa = *reinterpret_cast<const float4*>(xp);
            const float4 xb = *reinterpret_cast<const float4*>(xp + 4);
            xv[bb][0] = xa.x; xv[bb][1] = xa.y; xv[bb][2] = xa.z; xv[bb][3] = xa.w;
            xv[bb][4] = xb.x; xv[bb][5] = xb.y; xv[bb][6] = xb.z; xv[bb][7] = xb.w;
        }

        // u_hat[b, kk, j, dh*8+r] = sum_i x[b,j,i] * W[j,kk,i,dh*8+r]
        float uh[BW][8];
#pragma unroll
        for (int bb = 0; bb < BW; ++bb)
#pragma unroll
            for (int r = 0; r < 8; ++r) uh[bb][r] = 0.f;

        const char* wb = wlds + buf * SLICE;
#pragma unroll
        for (int i = 0; i < In; ++i) {
            const uint4 wv = *reinterpret_cast<const uint4*>(wb + ((Lb + i * 32) ^ kswz));
            float w8[8];
            {
                const __half2 h0 = *reinterpret_cast<const __half2*>(&wv.x);
                const __half2 h1 = *reinterpret_cast<const __half2*>(&wv.y);
                const __half2 h2 = *reinterpret_cast<const __half2*>(&wv.z);
                const __half2 h3 = *reinterpret_cast<const __half2*>(&wv.w);
                w8[0] = __low2float(h0); w8[1] = __high2float(h0);
                w8[2] = __low2float(h1); w8[3] = __high2float(h1);
                w8[4] = __low2float(h2); w8[5] = __high2float(h2);
                w8[6] = __low2float(h3); w8[7] = __high2float(h3);
            }
#pragma unroll
            for (int bb = 0; bb < BW; ++bb)
#pragma unroll
                for (int r = 0; r < 8; ++r)
                    uh[bb][r] = fmaf(xv[bb][i], w8[r], uh[bb][r]);
        }

        if (PHASE == 0) {
#pragma unroll
            for (int bb = 0; bb < BW; ++bb)
#pragma unroll
                for (int r = 0; r < 8; ++r) sacc[bb][r] += uh[bb][r];
        } else {
#pragma unroll
            for (int bb = 0; bb < BW; ++bb) {
                float p = vs[bb][0] * uh[bb][0];
#pragma unroll
                for (int r = 1; r < 8; ++r) p = fmaf(vs[bb][r], uh[bb][r], p);
                p += __shfl_xor(p, 1);   // combine d-halves -> full dot

                // no max-subtraction: |p| <= ~12 << 88, exp can't overflow.
                // masks 2..32 mix only same-parity lanes -> each k once.
                const float e = __expf(p);
                float ss = e;
#pragma unroll
                for (int mk = 2; mk <= 32; mk <<= 1)
                    ss += __shfl_xor(ss, mk);
#if __has_builtin(__builtin_amdgcn_rcpf)
                const float c = e * __builtin_amdgcn_rcpf(ss);
#else
                const float c = e / ss;
#endif
#pragma unroll
                for (int r = 0; r < 8; ++r)
                    sacc[bb][r] = fmaf(c, uh[bb][r], sacc[bb][r]);
            }
        }

        // finish the j+1 stage (regs arrived during compute), then issue j+2
        if (jj + 1 < JT) {
            write_stage(wlds + (buf ^ 1) * SLICE, tid, st);
            if (jj + 2 < JT) issue_loads(W, j0 + jj + 2, tid, st);
        }
        __syncthreads();   // buf reads done + next buf written
    }

    // epilogue: dump per-wave s partials
#pragma unroll
    for (int bb = 0; bb < BW; ++bb) {
        const int b = bbase + bb;
        const size_t cell = ((size_t)b * Kn + kk) * Dn + dh * 8;
        if (ATOMIC) {
#pragma unroll
            for (int r = 0; r < 8; ++r)
                atomicAdd(sout + cell + r, sacc[bb][r]);
        } else {
            const float4 f0 = make_float4(sacc[bb][0], sacc[bb][1], sacc[bb][2], sacc[bb][3]);
            const float4 f1 = make_float4(sacc[bb][4], sacc[bb][5], sacc[bb][6], sacc[bb][7]);
            float* dst = sout + (size_t)jb * CELLS + cell;
            *reinterpret_cast<float4*>(dst)     = f0;
            *reinterpret_cast<float4*>(dst + 4) = f1;
        }
    }
}

// Reduce partials, squash, update vsum; final phase writes v to d_out.
template <int PHASE, bool ATOMIC>
__global__ __launch_bounds__(256)
void squash_kernel(float* __restrict__ sbuf, float* __restrict__ vsum,
                   float* __restrict__ outv)
{
    const int t = blockIdx.x * blockDim.x + threadIdx.x;   // 0..16383
    const size_t c4 = (size_t)t * 4;

    float4 s;
    if (ATOMIC) {
        s = *reinterpret_cast<const float4*>(sbuf + c4);
        *reinterpret_cast<float4*>(sbuf + c4) = make_float4(0.f, 0.f, 0.f, 0.f);
    } else {
        s = make_float4(0.f, 0.f, 0.f, 0.f);
#pragma unroll 4
        for (int p = 0; p < NJB; ++p) {
            const float4 v = *reinterpret_cast<const float4*>(sbuf + (size_t)p * CELLS + c4);
            s.x += v.x; s.y += v.y; s.z += v.z; s.w += v.w;
        }
    }

    if (PHASE == 0) {  // uniform c = 1/K folded out of the sweep
        const float sc = 1.f / 32.f;
        s.x *= sc; s.y *= sc; s.z *= sc; s.w *= sc;
    }

    float s2 = s.x * s.x + s.y * s.y + s.z * s.z + s.w * s.w;
    s2 += __shfl_xor(s2, 1);
    s2 += __shfl_xor(s2, 2);
    const float scale = s2 / ((1.f + s2) * sqrtf(s2 + 1e-7f));
    const float4 v4 = make_float4(s.x * scale, s.y * scale, s.z * scale, s.w * scale);

    if (PHASE == 2) {
        *reinterpret_cast<float4*>(outv + c4) = v4;
    } else if (PHASE == 0) {
        *reinterpret_cast<float4*>(vsum + c4) = v4;
    } else {
        float4 o = *reinterpret_cast<const float4*>(vsum + c4);
        o.x += v4.x; o.y += v4.y; o.z += v4.z; o.w += v4.w;
        *reinterpret_cast<float4*>(vsum + c4) = o;
    }
}

extern "C" void kernel_launch(void* const* d_in, const int* in_sizes, int n_in,
                              void* d_out, int out_size, void* d_ws, size_t ws_size,
                              hipStream_t stream)
{
    const float* x = (const float*)d_in[0];
    const float* W = (const float*)d_in[1];
    float* out = (float*)d_out;

    const size_t partial_bytes = (size_t)NJB * CELLS * sizeof(float);  // 16 MB
    const size_t vsum_bytes    = (size_t)CELLS * sizeof(float);        // 256 KB

    const dim3 gs(GRID_SWEEP), bs(BLOCK);
    const dim3 gq(CELLS / 4 / 256), bq(256);

    if (ws_size >= partial_bytes + vsum_bytes) {
        float* partial = (float*)d_ws;
        float* vsum    = (float*)((char*)d_ws + partial_bytes);
        sweep_kernel<0, false><<<gs, bs, 0, stream>>>(x, W, vsum, partial);
        squash_kernel<0, false><<<gq, bq, 0, stream>>>(partial, vsum, out);
        sweep_kernel<1, false><<<gs, bs, 0, stream>>>(x, W, vsum, partial);
        squash_kernel<1, false><<<gq, bq, 0, stream>>>(partial, vsum, out);
        sweep_kernel<2, false><<<gs, bs, 0, stream>>>(x, W, vsum, partial);
        squash_kernel<2, false><<<gq, bq, 0, stream>>>(partial, vsum, out);
    } else {
        // tiny-workspace fallback: single accumulator + atomics
        float* sbuf = (float*)d_ws;
        float* vsum = (float*)((char*)d_ws + vsum_bytes);
        hipMemsetAsync(sbuf, 0, vsum_bytes, stream);
        sweep_kernel<0, true><<<gs, bs, 0, stream>>>(x, W, vsum, sbuf);
        squash_kernel<0, true><<<gq, bq, 0, stream>>>(sbuf, vsum, out);
        sweep_kernel<1, true><<<gs, bs, 0, stream>>>(x, W, vsum, sbuf);
        squash_kernel<1, true><<<gq, bq, 0, stream>>>(sbuf, vsum, out);
        sweep_kernel<2, true><<<gs, bs, 0, stream>>>(x, W, vsum, sbuf);
        squash_kernel<2, true><<<gq, bq, 0, stream>>>(sbuf, vsum, out);
    }
}